// Round 4
// baseline (273.372 us; speedup 1.0000x reference)
//
#include <hip/hip_runtime.h>
#include <math.h>

#define NN 50000
#define DD 128
#define HH 128
#define L1 64
#define L2 32
#define OO 10

// packed B-fragment table sizes (ct * ks * 64 lanes * 8 elems)
#define NW0 16384   // W : 8 ct * 4 ks * 64 * 8
#define NW1 8192    // W1: 4 ct * 4 ks * 64 * 8
#define NW2 2048    // W2: 2 ct * 2 ks * 64 * 8
#define NWT (NW0 + NW1 + NW2)

typedef short v8s __attribute__((ext_vector_type(8)));   // 8 bf16 (4 VGPRs)
typedef float v4f __attribute__((ext_vector_type(4)));   // MFMA accumulator

// ---- bf16 helpers (manual: RNE pack) ----
__device__ __forceinline__ float bf2f_lo(unsigned u) { return __uint_as_float(u << 16); }
__device__ __forceinline__ float bf2f_hi(unsigned u) { return __uint_as_float(u & 0xffff0000u); }
__device__ __forceinline__ unsigned short f2bf(float f) {
    unsigned u = __float_as_uint(f);
    return (unsigned short)((u + 0x7fffu + ((u >> 16) & 1u)) >> 16);
}
__device__ __forceinline__ unsigned pack2(float lo, float hi) {
    return (unsigned)f2bf(lo) | ((unsigned)f2bf(hi) << 16);
}
__device__ __forceinline__ float gelu_f(float v) {
    return 0.5f * v * (1.f + erff(v * 0.70710678118654752f));
}

// ---------------- K1: weights pack + x->bf16 interleave + histogram + ss fill --
__global__ __launch_bounds__(256) void k_prep(
    const float* __restrict__ x, unsigned short* __restrict__ xb,
    const int* __restrict__ ei, int* __restrict__ counts,
    const float* __restrict__ W, const float* __restrict__ W1,
    const float* __restrict__ W2, unsigned short* __restrict__ wtp,
    unsigned short* __restrict__ w1tp, unsigned short* __restrict__ w2tp,
    int* __restrict__ ssf, int nfill, unsigned* __restrict__ zrow, int E)
{
    const int gid = blockIdx.x * 256 + threadIdx.x;
    const int stride = gridDim.x * 256;

    // packed MFMA B-fragment tables: ((ct*KS+ks)*64+lane)*8+e = Wx[k][n],
    // k = ks*32+(lane>>4)*8+e, n = ct*16+(lane&15)
    for (int i = gid; i < NWT; i += stride) {
        if (i < NW0) {
            const int e = i & 7, ln = (i >> 3) & 63, ks = (i >> 9) & 3, ct = i >> 11;
            wtp[i] = f2bf(W[(ks * 32 + (ln >> 4) * 8 + e) * HH + ct * 16 + (ln & 15)]);
        } else if (i < NW0 + NW1) {
            const int j = i - NW0;
            const int e = j & 7, ln = (j >> 3) & 63, ks = (j >> 9) & 3, ct = j >> 11;
            w1tp[j] = f2bf(W1[(ks * 32 + (ln >> 4) * 8 + e) * L1 + ct * 16 + (ln & 15)]);
        } else {
            const int j = i - NW0 - NW1;
            const int e = j & 7, ln = (j >> 3) & 63, ks = (j >> 9) & 1, ct = j >> 10;
            w2tp[j] = f2bf(W2[(ks * 32 + (ln >> 4) * 8 + e) * L2 + ct * 16 + (ln & 15)]);
        }
    }
    // dummy zero row (512 B) for CSR padding
    if (zrow != nullptr && gid < 128) zrow[gid] = 0u;
    // pre-fill ss with dummy node index (pad slots survive k_bucket)
    for (int i = gid; i < nfill; i += stride) ssf[i] = NN;
    // x -> interleaved bf16
    const int HALF = NN * 32;                 // float4-chunks per batch
    for (int idx = gid; idx < 2 * HALF; idx += stride) {
        const int b = (idx >= HALF) ? 1 : 0;
        const int j = idx - b * HALF;
        const int n = j >> 5;
        const int c4 = j & 31;
        const float4 v = *(const float4*)(x + ((size_t)b * NN + n) * DD + c4 * 4);
        ushort4 o;
        o.x = f2bf(v.x); o.y = f2bf(v.y); o.z = f2bf(v.z); o.w = f2bf(v.w);
        *(ushort4*)(xb + ((size_t)n * 2 + b) * DD + c4 * 4) = o;
    }
    // dst histogram
    for (int e = gid; e < E; e += stride)
        atomicAdd(&counts[ei[(size_t)E + e]], 1);
}

// ---------------- multi-block scan, stage 1 (over 8-padded degrees) -----------
__global__ __launch_bounds__(1024) void k_scan1(
    const int* __restrict__ counts, int* __restrict__ offsets,
    int* __restrict__ blksum, int n)
{
    __shared__ int wsum[16], woff[16];
    const int tid = threadIdx.x, lane = tid & 63, wv = tid >> 6;
    const int i = blockIdx.x * 1024 + tid;
    int v = (i < n) ? ((counts[i] + 7) & ~7) : 0;
    int x = v;
    #pragma unroll
    for (int d = 1; d < 64; d <<= 1) { int t = __shfl_up(x, d); if (lane >= d) x += t; }
    if (lane == 63) wsum[wv] = x;
    __syncthreads();
    if (wv == 0 && lane < 16) {
        int y = wsum[lane];
        #pragma unroll
        for (int d = 1; d < 16; d <<= 1) { int t = __shfl_up(y, d); if (lane >= d) y += t; }
        woff[lane] = y - wsum[lane];
        if (lane == 15) blksum[blockIdx.x] = y;
    }
    __syncthreads();
    if (i < n) offsets[i] = woff[wv] + (x - v);
}

// ---------------- multi-block scan, stage 2 ----------------
__global__ __launch_bounds__(1024) void k_scan2(
    int* __restrict__ offsets, const int* __restrict__ blksum, int nblk, int n)
{
    __shared__ int base_sh, tot_sh;
    const int tid = threadIdx.x, lane = tid & 63, wv = tid >> 6;
    if (wv == 0) {
        int v = (lane < nblk) ? blksum[lane] : 0;
        int x = v;
        #pragma unroll
        for (int d = 1; d < 64; d <<= 1) { int t = __shfl_up(x, d); if (lane >= d) x += t; }
        int incl = __shfl(x, blockIdx.x);
        int own  = __shfl(v, blockIdx.x);
        int tot  = __shfl(x, nblk - 1);
        if (lane == 0) { base_sh = incl - own; tot_sh = tot; }
    }
    __syncthreads();
    const int i = blockIdx.x * 1024 + tid;
    if (i < n) offsets[i] += base_sh;
    if (blockIdx.x == nblk - 1 && tid == 0) offsets[n] = tot_sh;
}

// ---------------- CSR build: bucket src indices by dst ----------------
__global__ __launch_bounds__(256) void k_bucket(
    const int* __restrict__ ei, const int* __restrict__ offsets,
    int* __restrict__ cursor, int* __restrict__ ss, int E)
{
    int e = blockIdx.x * 256 + threadIdx.x;
    if (e < E) {
        int d = ei[E + e];
        int pos = offsets[d] + atomicAdd(&cursor[d], 1);
        ss[pos] = ei[e];
    }
}

// ---------------- K3: fused gather-agg + (agg @ W) + gelu + MLP + colsums ----
// Block: 32 nodes (64 storage rows), 512 threads (8 waves).
// Gather: segments 8-padded -> branch-free loop; per wave: 1 aligned uint4
// index load (lo-half edges i..i+3, hi-half i+4..i+7) + 4 independent 1KB
// row loads in flight (4 KB/wave). Pad edges hit the L1-resident zero row.
template<bool FUSED>
__global__ __launch_bounds__(512, 6) void k_mlp_t(
    const unsigned short* __restrict__ src,   // FUSED ? xb : aggb
    const int* __restrict__ offsets, const int* __restrict__ ss,
    const unsigned short* __restrict__ wtp, const float* __restrict__ b0v,
    const unsigned short* __restrict__ w1tp, const float* __restrict__ b1v,
    const unsigned short* __restrict__ w2tp, const float* __restrict__ b2v,
    float* __restrict__ partials, int srows)
{
    __shared__ __align__(16) unsigned char upool[64 * 136 * 2]; // xa/hsb/h2p
    __shared__ __align__(16) unsigned short h1b[64 * 72];       // 9.2 KB
    __shared__ float b0s[DD], b1s[L1], b2s[L2];
    __shared__ float oacc[64];
    unsigned short* xa  = (unsigned short*)upool;   // [64][136] bf16 agg tile
    unsigned short* hsb = (unsigned short*)upool;   // [64][136] bf16 (after xa dead)
    float* h2p = (float*)upool;                     // [64][36] f32 (after hsb dead)

    const int tid = threadIdx.x;
    const int row0 = blockIdx.x * 64;
    const int lane = tid & 63;
    const int w = tid >> 6;       // 0..7

    if (tid < DD) b0s[tid] = b0v[tid];
    if (tid < L1) b1s[tid] = b1v[tid];
    if (tid < L2) b2s[tid] = b2v[tid];
    if (tid < 64) oacc[tid] = 0.f;

    if (FUSED) {
        const int half4 = (lane >> 5) * 4;         // 0 | 4
        const int co = (lane & 31) * 8;            // shorts offset in 512B row
        #pragma unroll
        for (int j = 0; j < 4; ++j) {
            const int ln = w * 4 + j;              // block-local node 0..31
            const int d = blockIdx.x * 32 + ln;    // global node
            int s0 = 0, s1 = 0;
            if (d < NN) { s0 = offsets[d]; s1 = offsets[d + 1]; }
            float a[8];
            #pragma unroll
            for (int t = 0; t < 8; ++t) a[t] = 0.f;
            for (int i = s0; i < s1; i += 8) {
                const uint4 idx = *(const uint4*)(ss + i + half4);
                const uint4 r0 = *(const uint4*)(src + (size_t)idx.x * 256 + co);
                const uint4 r1 = *(const uint4*)(src + (size_t)idx.y * 256 + co);
                const uint4 r2 = *(const uint4*)(src + (size_t)idx.z * 256 + co);
                const uint4 r3 = *(const uint4*)(src + (size_t)idx.w * 256 + co);
                a[0] += bf2f_lo(r0.x); a[1] += bf2f_hi(r0.x);
                a[2] += bf2f_lo(r0.y); a[3] += bf2f_hi(r0.y);
                a[4] += bf2f_lo(r0.z); a[5] += bf2f_hi(r0.z);
                a[6] += bf2f_lo(r0.w); a[7] += bf2f_hi(r0.w);
                a[0] += bf2f_lo(r1.x); a[1] += bf2f_hi(r1.x);
                a[2] += bf2f_lo(r1.y); a[3] += bf2f_hi(r1.y);
                a[4] += bf2f_lo(r1.z); a[5] += bf2f_hi(r1.z);
                a[6] += bf2f_lo(r1.w); a[7] += bf2f_hi(r1.w);
                a[0] += bf2f_lo(r2.x); a[1] += bf2f_hi(r2.x);
                a[2] += bf2f_lo(r2.y); a[3] += bf2f_hi(r2.y);
                a[4] += bf2f_lo(r2.z); a[5] += bf2f_hi(r2.z);
                a[6] += bf2f_lo(r2.w); a[7] += bf2f_hi(r2.w);
                a[0] += bf2f_lo(r3.x); a[1] += bf2f_hi(r3.x);
                a[2] += bf2f_lo(r3.y); a[3] += bf2f_hi(r3.y);
                a[4] += bf2f_lo(r3.z); a[5] += bf2f_hi(r3.z);
                a[6] += bf2f_lo(r3.w); a[7] += bf2f_hi(r3.w);
            }
            #pragma unroll
            for (int t = 0; t < 8; ++t) a[t] += __shfl_xor(a[t], 32);
            if (lane < 32) {
                const int tr = ln * 2 + (lane >> 4);   // storage row in tile
                const int col = (lane & 15) * 8;
                uint4 o;
                o.x = pack2(a[0], a[1]); o.y = pack2(a[2], a[3]);
                o.z = pack2(a[4], a[5]); o.w = pack2(a[6], a[7]);
                *(uint4*)(&xa[tr * 136 + col]) = o;
            }
        }
    } else {
        // stage pre-aggregated tile (fallback path)
        for (int u = tid * 8; u < 64 * DD; u += 4096) {
            const int r = u >> 7, c = u & 127;
            uint4 raw = make_uint4(0, 0, 0, 0);
            if (row0 + r < srows) raw = *(const uint4*)(src + (size_t)(row0 + r) * HH + c);
            *(uint4*)(&xa[r * 136 + c]) = raw;
        }
    }
    __syncthreads();

    const int lm = lane & 15;
    const int q = lane >> 4;
    const int r1 = (w & 3) * 16;  // row-tile base
    const int ch = w >> 2;        // column half 0/1

    // W-GEMM (64x128 @ 128x128): wave w -> rows r1..+16, cols ch*64..+64
    {
        v4f acc[4];
        #pragma unroll
        for (int i = 0; i < 4; ++i) acc[i] = (v4f)(0.f);
        #pragma unroll
        for (int ks = 0; ks < 4; ++ks) {
            const int k0 = ks * 32 + q * 8;
            const v8s af = *(const v8s*)(&xa[(r1 + lm) * 136 + k0]);
            #pragma unroll
            for (int ct = 0; ct < 4; ++ct) {
                const int ctg = ch * 4 + ct;
                const v8s bf = *(const v8s*)(wtp + ((size_t)(ctg * 4 + ks) * 64 + lane) * 8);
                acc[ct] = __builtin_amdgcn_mfma_f32_16x16x32_bf16(af, bf, acc[ct], 0, 0, 0);
            }
        }
        __syncthreads();   // all xa reads done; upool becomes hsb

        // bias + gelu -> hsb (A-operand layout for layer1)
        #pragma unroll
        for (int ct = 0; ct < 4; ++ct) {
            const int col = ch * 64 + ct * 16 + lm;
            const float bias = b0s[col];
            #pragma unroll
            for (int r = 0; r < 4; ++r)
                hsb[(r1 + q * 4 + r) * 136 + col] = f2bf(gelu_f(acc[ct][r] + bias));
        }
    }
    __syncthreads();

    // layer1 (64x128 @ 128x64): wave w -> rows r1..+16, cols ch*32..+32
    {
        v4f a1[2];
        a1[0] = (v4f)(0.f); a1[1] = (v4f)(0.f);
        #pragma unroll
        for (int ks = 0; ks < 4; ++ks) {
            const int k0 = ks * 32 + q * 8;
            const v8s af = *(const v8s*)(&hsb[(r1 + lm) * 136 + k0]);
            #pragma unroll
            for (int ct = 0; ct < 2; ++ct) {
                const int ctg = ch * 2 + ct;
                const v8s bf = *(const v8s*)(w1tp + ((size_t)(ctg * 4 + ks) * 64 + lane) * 8);
                a1[ct] = __builtin_amdgcn_mfma_f32_16x16x32_bf16(af, bf, a1[ct], 0, 0, 0);
            }
        }
        #pragma unroll
        for (int ct = 0; ct < 2; ++ct) {
            const int col = ch * 32 + ct * 16 + lm;
            const float bias = b1s[col];
            #pragma unroll
            for (int r = 0; r < 4; ++r)
                h1b[(r1 + q * 4 + r) * 72 + col] = f2bf(fmaxf(a1[ct][r] + bias, 0.f));
        }
    }
    __syncthreads();

    // layer2 (64x64 @ 64x32): wave w -> rows r1..+16, cols ch*16..+16
    {
        v4f a2 = (v4f)(0.f);
        #pragma unroll
        for (int ks = 0; ks < 2; ++ks) {
            const int k0 = ks * 32 + q * 8;
            const v8s af = *(const v8s*)(&h1b[(r1 + lm) * 72 + k0]);
            const v8s bf = *(const v8s*)(w2tp + ((size_t)(ch * 2 + ks) * 64 + lane) * 8);
            a2 = __builtin_amdgcn_mfma_f32_16x16x32_bf16(af, bf, a2, 0, 0, 0);
        }
        __syncthreads();   // hsb (upool) reads long done; reuse as h2p
        const int col = ch * 16 + lm;
        const float bias = b2s[col];
        #pragma unroll
        for (int r = 0; r < 4; ++r)
            h2p[(r1 + q * 4 + r) * 36 + col] = fmaxf(a2[r] + bias, 0.f);
    }
    __syncthreads();

    // column sums: storage row r -> batch r&1
    {
        const int c = tid & 31;
        const int g = tid >> 5;   // 0..15, 4 rows each
        float p0 = 0.f, p1 = 0.f;
        #pragma unroll
        for (int i = 0; i < 4; ++i) {
            const int r = g * 4 + i;
            if (row0 + r < srows) {
                const float v = h2p[r * 36 + c];
                if (r & 1) p1 += v; else p0 += v;
            }
        }
        if (p0 != 0.f) atomicAdd(&oacc[c], p0);
        if (p1 != 0.f) atomicAdd(&oacc[32 + c], p1);
    }
    __syncthreads();
    if (tid < 64) partials[(size_t)blockIdx.x * 64 + tid] = oacc[tid];
}

// ---------------- Fallback path (ws too small for CSR) ----------------
__global__ __launch_bounds__(256) void k_scatter(
    const int* __restrict__ ei, const unsigned short* __restrict__ xb,
    float* __restrict__ aggf, int E)
{
    const int tid = threadIdx.x;
    const int eg = tid >> 6;
    const int lane = tid & 63;
    const int e = blockIdx.x * 4 + eg;
    if (e >= E) return;
    const int src = ei[e];
    const int dst = ei[E + e];
    const uint2 r = *(const uint2*)(xb + (size_t)src * 256 + lane * 4);
    float* ap = aggf + (size_t)dst * 256 + lane * 4;
    unsafeAtomicAdd(ap + 0, bf2f_lo(r.x));
    unsafeAtomicAdd(ap + 1, bf2f_hi(r.x));
    unsafeAtomicAdd(ap + 2, bf2f_lo(r.y));
    unsafeAtomicAdd(ap + 3, bf2f_hi(r.y));
}

__global__ __launch_bounds__(256) void k_cvt(
    const float* __restrict__ in, unsigned short* __restrict__ outb, int n)
{
    int i = blockIdx.x * 256 + threadIdx.x;
    if (i < n) outb[i] = f2bf(in[i]);
}

// ---------------- K4: reduce partials + last-block applies layer3 -------------
__global__ __launch_bounds__(256) void k_reduce_final(
    const float* __restrict__ partials, float* __restrict__ accum, int nblk,
    int* __restrict__ dcnt, const float* __restrict__ W3,
    const float* __restrict__ b3v, float* __restrict__ out)
{
    __shared__ float lsum[4][64];
    __shared__ int lastf;
    const int t = threadIdx.x & 63;
    const int w = threadIdx.x >> 6;
    float s = 0.f;
    for (int g = blockIdx.x * 4 + w; g < nblk; g += gridDim.x * 4)
        s += partials[(size_t)g * 64 + t];
    lsum[w][t] = s;
    __syncthreads();
    if (threadIdx.x < 64) {
        const float v = lsum[0][t] + lsum[1][t] + lsum[2][t] + lsum[3][t];
        unsafeAtomicAdd(&accum[t], v);
    }
    __threadfence();                      // release: accum atomics visible
    __syncthreads();
    if (threadIdx.x == 0)
        lastf = (atomicAdd(dcnt, 1) == (int)gridDim.x - 1) ? 1 : 0;
    __syncthreads();
    if (lastf && threadIdx.x < 2 * OO) {
        const int b = threadIdx.x / OO, o = threadIdx.x % OO;
        float acc = b3v[o];
        const float inv = 1.0f / (float)NN;
        #pragma unroll
        for (int j = 0; j < L2; ++j)
            acc += (unsafeAtomicAdd(&accum[b * 32 + j], 0.f) * inv) * W3[j * OO + o];
        out[threadIdx.x] = acc;
    }
}

extern "C" void kernel_launch(void* const* d_in, const int* in_sizes, int n_in,
                              void* d_out, int out_size, void* d_ws, size_t ws_size,
                              hipStream_t stream) {
    const float* x  = (const float*)d_in[0];
    const int*   ei = (const int*)d_in[1];
    const float* W  = (const float*)d_in[2];
    const float* b0 = (const float*)d_in[3];
    const float* W1 = (const float*)d_in[4];
    const float* b1 = (const float*)d_in[5];
    const float* W2 = (const float*)d_in[6];
    const float* b2 = (const float*)d_in[7];
    const float* W3 = (const float*)d_in[8];
    const float* b3 = (const float*)d_in[9];
    float* out = (float*)d_out;

    const int E = in_sizes[1] / 2;           // 800000
    const int rows = 2 * NN;                 // 100000 storage rows
    const int nblk = (rows + 63) / 64;       // 1563 (mlp blocks, 32 nodes each)
    const int nsb = (NN + 1023) / 1024;      // 49 scan blocks
    const int SSN = E + 7 * NN + 8;          // padded CSR capacity

    // ---- CSR-path workspace layout ----
    unsigned short* xb = (unsigned short*)d_ws;                      // rows*HH bf16
    unsigned* zrow     = (unsigned*)(xb + (size_t)rows * HH);        // 512 B zero row
    int*   ss       = (int*)(zrow + 128);                            // SSN ints
    float* partials = (float*)(ss + SSN);                            // nblk*64
    float* accum    = partials + (size_t)nblk * 64;                  // 64
    int*   dcnt     = (int*)(accum + 64);                            // 16
    int*   counts   = dcnt + 16;                                     // NN
    int*   cursor   = counts + NN;                                   // NN
    int*   offsets  = cursor + NN;                                   // NN+1
    int*   blksum   = offsets + NN + 1;                              // 64
    unsigned short* wtp = (unsigned short*)(((uintptr_t)(blksum + 64) + 15) & ~(uintptr_t)15);
    unsigned short* w1tp = wtp + NW0;
    unsigned short* w2tp = w1tp + NW1;
    const size_t need_csr = (size_t)((unsigned short*)(w2tp + NW2) - (unsigned short*)d_ws)
                            * sizeof(unsigned short) + 16;

    // ---- fallback workspace layout (old scheme) ----
    unsigned short* f_aggb = xb + (size_t)rows * HH;
    float* f_partials = (float*)(f_aggb + (size_t)rows * HH);
    float* f_accum    = f_partials + (size_t)nblk * 64;
    int*   f_dcnt     = (int*)(f_accum + 64);
    unsigned short* f_wtp = (unsigned short*)(((uintptr_t)(f_dcnt + 16) + 15) & ~(uintptr_t)15);
    unsigned short* f_w1tp = f_wtp + NW0;
    unsigned short* f_w2tp = f_w1tp + NW1;
    float* f_aggf     = (float*)(((uintptr_t)(f_w2tp + NW2) + 15) & ~(uintptr_t)15);
    const size_t need_fb = (size_t)((char*)(f_aggf + (size_t)rows * HH) - (char*)d_ws) + 16;

    if (ws_size >= need_csr && nsb <= 64) {
        hipMemsetAsync(accum, 0, (80 + 2 * (size_t)NN) * sizeof(int), stream);
        k_prep<<<dim3(2048), dim3(256), 0, stream>>>(
            x, xb, ei, counts, W, W1, W2, wtp, w1tp, w2tp, ss, SSN, zrow, E);
        k_scan1<<<dim3(nsb), dim3(1024), 0, stream>>>(counts, offsets, blksum, NN);
        k_scan2<<<dim3(nsb), dim3(1024), 0, stream>>>(offsets, blksum, nsb, NN);
        k_bucket<<<dim3((E + 255) / 256), dim3(256), 0, stream>>>(ei, offsets, cursor, ss, E);
        k_mlp_t<true><<<dim3(nblk), dim3(512), 0, stream>>>(
            xb, offsets, ss, wtp, b0, w1tp, b1, w2tp, b2, partials, rows);
        k_reduce_final<<<dim3(64), dim3(256), 0, stream>>>(
            partials, accum, nblk, dcnt, W3, b3, out);
    } else if (ws_size >= need_fb) {
        hipMemsetAsync(f_accum, 0, 80 * sizeof(int), stream);
        hipMemsetAsync(f_aggf, 0, (size_t)rows * HH * sizeof(float), stream);
        k_prep<<<dim3(2048), dim3(256), 0, stream>>>(
            x, xb, ei, (int*)f_dcnt /*unused*/, W, W1, W2, f_wtp, f_w1tp, f_w2tp,
            (int*)f_dcnt, 0, nullptr, 0);
        k_scatter<<<dim3((E + 3) / 4), dim3(256), 0, stream>>>(ei, xb, f_aggf, E);
        k_cvt<<<dim3((rows * HH + 255) / 256), dim3(256), 0, stream>>>(f_aggf, f_aggb, rows * HH);
        k_mlp_t<false><<<dim3(nblk), dim3(512), 0, stream>>>(
            f_aggb, nullptr, nullptr, f_wtp, b0, f_w1tp, b1, f_w2tp, b2, f_partials, rows);
        k_reduce_final<<<dim3(64), dim3(256), 0, stream>>>(
            f_partials, f_accum, nblk, f_dcnt, W3, b3, out);
    }
}